// Round 8
// baseline (3731.618 us; speedup 1.0000x reference)
//
#include <hip/hip_runtime.h>
#include <hip/hip_cooperative_groups.h>
#include <stdint.h>

namespace cg = cooperative_groups;

// Show-Attend-Tell forward, MI355X. B=128, P=196, E=2048, H=512, V=10000, T=20.
// R6: whole 20-step recurrence in ONE persistent cooperative kernel (grid=256),
// 2 grid.sync()/step. Phase1: attention(blk 0..127) || h@[fbT|WhhT] (blk 128..255).
// Phase2: 256 x (32x32 gate tile) GEMM K=2048 with on-the-fly A and LSTM epilogue.

typedef unsigned short u16;
typedef unsigned int u32;
typedef __attribute__((ext_vector_type(8))) short bf16x8;
typedef __attribute__((ext_vector_type(4))) float f32x4;

__device__ __forceinline__ float bf2f(u16 u) { return __uint_as_float(((u32)u) << 16); }
__device__ __forceinline__ u16 f2bf(float f) {
  u32 x = __float_as_uint(f);
  u32 r = x + 0x7fffu + ((x >> 16) & 1u);
  return (u16)(r >> 16);
}
__device__ __forceinline__ float tanh_f(float x) {
  x = fminf(15.f, fmaxf(-15.f, x));
  float e = __expf(2.f * x);
  return 1.f - 2.f * __builtin_amdgcn_rcpf(e + 1.f);
}
__device__ __forceinline__ float sigm_f(float x) {
  x = fminf(30.f, fmaxf(-30.f, x));
  return __builtin_amdgcn_rcpf(1.f + __expf(-x));
}

// ---- conversion: f32 -> bf16, 8 elems/thread ------------------------------
__global__ __launch_bounds__(256) void k_f32_to_bf16(const float* __restrict__ in,
                                                     u16* __restrict__ out) {
  size_t i = ((size_t)blockIdx.x * 256 + threadIdx.x) * 8;
  float4 v0 = *(const float4*)(in + i);
  float4 v1 = *(const float4*)(in + i + 4);
  union { u16 u[8]; uint4 v; } r;
  r.u[0] = f2bf(v0.x); r.u[1] = f2bf(v0.y); r.u[2] = f2bf(v0.z); r.u[3] = f2bf(v0.w);
  r.u[4] = f2bf(v1.x); r.u[5] = f2bf(v1.y); r.u[6] = f2bf(v1.z); r.u[7] = f2bf(v1.w);
  *(uint4*)(out + i) = r.v;
}

// ---- mean over P of imgb -> avgb bf16 -------------------------------------
__global__ __launch_bounds__(256) void k_avg(const u16* __restrict__ imgb,
                                             u16* __restrict__ avgb) {
  int b = blockIdx.y;
  int c0 = blockIdx.x * 512 + threadIdx.x * 2;
  const u32* p0 = (const u32*)(imgb + (size_t)b * 196 * 2048 + c0);
  float s0 = 0.f, s1 = 0.f;
  for (int p = 0; p < 196; ++p) {
    u32 v = p0[(size_t)p * 1024];
    s0 += bf2f((u16)(v & 0xffff));
    s1 += bf2f((u16)(v >> 16));
  }
  const float inv = 1.f / 196.f;
  u32 o = ((u32)f2bf(s1 * inv) << 16) | (u32)f2bf(s0 * inv);
  *(u32*)(avgb + (size_t)b * 2048 + c0) = o;
}

// ---- transpose f32[R,C] -> bf16[Cpad, R]; PERM = LSTM gate interleave -----
template <bool PERM>
__global__ __launch_bounds__(256) void k_transpose_bf16(const float* __restrict__ in,
                                                        int R, int C, int Cpad,
                                                        u16* __restrict__ out, int out_ld) {
  __shared__ float tile[32][33];
  int c0 = blockIdx.x * 32, r0 = blockIdx.y * 32;
  int tx = threadIdx.x, ty = threadIdx.y;  // (32, 8)
#pragma unroll
  for (int i = 0; i < 32; i += 8) {
    int r = r0 + ty + i, c = c0 + tx;
    tile[ty + i][tx] = (r < R && c < C) ? in[(size_t)r * C + c] : 0.f;
  }
  __syncthreads();
#pragma unroll
  for (int i = 0; i < 32; i += 8) {
    int c = c0 + ty + i, r = r0 + tx;
    if (c < Cpad && r < R) {
      int co = PERM ? ((c & 511) * 4 + (c >> 9)) : c;
      out[(size_t)co * out_ld + r] = f2bf(tile[tx][ty + i]);
    }
  }
}

// ---- cbias[perm(n)] = emb0 @ Wih + bih + bhh ------------------------------
__global__ __launch_bounds__(256) void k_cbias(const float* __restrict__ emb,
                                               const float* __restrict__ Wih,
                                               const float* __restrict__ bih,
                                               const float* __restrict__ bhh,
                                               float* __restrict__ cb) {
  __shared__ float e0[512];
  int tid = threadIdx.x;
  for (int i = tid; i < 512; i += 256) e0[i] = emb[i];
  __syncthreads();
  int n = blockIdx.x * 256 + tid;
  float s = bih[n] + bhh[n];
  for (int k = 0; k < 512; ++k) s += e0[k] * Wih[(size_t)k * 2048 + n];
  cb[(n & 511) * 4 + (n >> 9)] = s;
}

// ---- 64x64-tile MFMA GEMM (setup h0/c0 only) ------------------------------
enum { EPI_TANH_H = 0, EPI_TANH_C };

template <int EPI>
__global__ __launch_bounds__(256) void k_gemm64(
    const u16* __restrict__ A, const u16* __restrict__ BT, int K, int Ntiles,
    const float* __restrict__ bias, float* __restrict__ outF, u16* __restrict__ outB) {
  __shared__ __align__(16) u16 Asm[64 * 72];
  __shared__ __align__(16) u16 Bsm[64 * 72];
  int bid = blockIdx.x;
  int mt = bid / Ntiles, nt = bid % Ntiles;
  long m0 = (long)mt * 64, n0 = (long)nt * 64;
  int tid = threadIdx.x, lane = tid & 63, w = tid >> 6;
  int srow = tid >> 3, schk = tid & 7;
  f32x4 acc[4] = {};
  const u16* Ap0 = A + (m0 + srow) * K + schk * 8;
  const u16* Ap1 = A + (m0 + srow + 32) * K + schk * 8;
  const u16* Bp0 = BT + (n0 + srow) * K + schk * 8;
  const u16* Bp1 = BT + (n0 + srow + 32) * K + schk * 8;
  u16* Aw0 = Asm + srow * 72 + schk * 8;
  u16* Aw1 = Asm + (srow + 32) * 72 + schk * 8;
  u16* Bw0 = Bsm + srow * 72 + schk * 8;
  u16* Bw1 = Bsm + (srow + 32) * 72 + schk * 8;
  const u16* Ar = Asm + (w * 16 + (lane & 15)) * 72 + (lane >> 4) * 8;
  const u16* Br = Bsm + (lane & 15) * 72 + (lane >> 4) * 8;
  for (int k0 = 0; k0 < K; k0 += 64) {
    uint4 a0 = *(const uint4*)(Ap0 + k0);
    uint4 a1 = *(const uint4*)(Ap1 + k0);
    uint4 b0 = *(const uint4*)(Bp0 + k0);
    uint4 b1 = *(const uint4*)(Bp1 + k0);
    __syncthreads();
    *(uint4*)Aw0 = a0;
    *(uint4*)Aw1 = a1;
    *(uint4*)Bw0 = b0;
    *(uint4*)Bw1 = b1;
    __syncthreads();
#pragma unroll
    for (int kk = 0; kk < 2; ++kk) {
      bf16x8 af = *(const bf16x8*)(Ar + kk * 32);
#pragma unroll
      for (int sn = 0; sn < 4; ++sn) {
        bf16x8 bfr = *(const bf16x8*)(Br + sn * 16 * 72 + kk * 32);
        acc[sn] = __builtin_amdgcn_mfma_f32_16x16x32_bf16(af, bfr, acc[sn], 0, 0, 0);
      }
    }
  }
  int cb = lane & 15, rb = (lane >> 4) * 4;
#pragma unroll
  for (int sn = 0; sn < 4; ++sn) {
#pragma unroll
    for (int r = 0; r < 4; ++r) {
      long m = m0 + w * 16 + rb + r;
      long n = n0 + sn * 16 + cb;
      float v = acc[sn][r] + bias[n];
      if (EPI == EPI_TANH_H) outB[m * 512 + n] = f2bf(tanh_f(v));
      else outF[m * 512 + n] = tanh_f(v);
    }
  }
}

// ---- 128x128-tile MFMA GEMM (Ws + final out) ------------------------------
enum { EPI128_WS = 0, EPI128_OUT };

template <int EPI>
__global__ __launch_bounds__(256) void k_gemm128(
    const u16* __restrict__ A, const u16* __restrict__ BT, int K, int Ntiles,
    const float* __restrict__ bias, float* __restrict__ outF,
    u16* __restrict__ outB, int ncap) {
  __shared__ __align__(16) u16 Asm[128 * 72];
  __shared__ __align__(16) u16 Bsm[128 * 72];
  int bid = blockIdx.x;
  int mt = bid / Ntiles, nt = bid % Ntiles;
  long m0 = (long)mt * 128, n0 = (long)nt * 128;
  int tid = threadIdx.x, lane = tid & 63, w = tid >> 6;
  int wr = w >> 1, wc = w & 1;
  int srow = tid >> 3, schk = tid & 7;
  f32x4 acc[4][4] = {};
  const u16* Ap = A + (m0 + srow) * K + schk * 8;
  const u16* Bp = BT + (n0 + srow) * K + schk * 8;
  u16* Aw = Asm + srow * 72 + schk * 8;
  u16* Bw = Bsm + srow * 72 + schk * 8;
  const u16* Ar = Asm + (wr * 64 + (lane & 15)) * 72 + (lane >> 4) * 8;
  const u16* Br = Bsm + (wc * 64 + (lane & 15)) * 72 + (lane >> 4) * 8;
  for (int k0 = 0; k0 < K; k0 += 64) {
    uint4 a0 = *(const uint4*)(Ap + k0);
    uint4 a1 = *(const uint4*)(Ap + (size_t)32 * K + k0);
    uint4 a2 = *(const uint4*)(Ap + (size_t)64 * K + k0);
    uint4 a3 = *(const uint4*)(Ap + (size_t)96 * K + k0);
    uint4 b0 = *(const uint4*)(Bp + k0);
    uint4 b1 = *(const uint4*)(Bp + (size_t)32 * K + k0);
    uint4 b2 = *(const uint4*)(Bp + (size_t)64 * K + k0);
    uint4 b3 = *(const uint4*)(Bp + (size_t)96 * K + k0);
    __syncthreads();
    *(uint4*)Aw = a0;
    *(uint4*)(Aw + 32 * 72) = a1;
    *(uint4*)(Aw + 64 * 72) = a2;
    *(uint4*)(Aw + 96 * 72) = a3;
    *(uint4*)Bw = b0;
    *(uint4*)(Bw + 32 * 72) = b1;
    *(uint4*)(Bw + 64 * 72) = b2;
    *(uint4*)(Bw + 96 * 72) = b3;
    __syncthreads();
#pragma unroll
    for (int kk = 0; kk < 2; ++kk) {
      bf16x8 af[4], bfv[4];
#pragma unroll
      for (int i = 0; i < 4; ++i) {
        af[i] = *(const bf16x8*)(Ar + i * 16 * 72 + kk * 32);
        bfv[i] = *(const bf16x8*)(Br + i * 16 * 72 + kk * 32);
      }
#pragma unroll
      for (int sm = 0; sm < 4; ++sm)
#pragma unroll
        for (int sn = 0; sn < 4; ++sn)
          acc[sm][sn] = __builtin_amdgcn_mfma_f32_16x16x32_bf16(af[sm], bfv[sn],
                                                                acc[sm][sn], 0, 0, 0);
    }
  }
  int cb = lane & 15, rb = (lane >> 4) * 4;
#pragma unroll
  for (int sm = 0; sm < 4; ++sm) {
#pragma unroll
    for (int sn = 0; sn < 4; ++sn) {
#pragma unroll
      for (int r = 0; r < 4; ++r) {
        long m = m0 + wr * 64 + sm * 16 + rb + r;
        long n = n0 + wc * 64 + sn * 16 + cb;
        float v = acc[sm][sn][r];
        if (EPI == EPI128_WS) {
          outB[m * 512 + n] = f2bf(v + bias[n]);
        } else {
          if (n < ncap) {
            long t = m >> 7, b = m & 127;
            outF[b * 200000 + t * 10000 + n] = v + bias[n];
          }
        }
      }
    }
  }
}

// ---- persistent cooperative loop kernel -----------------------------------
__global__ __launch_bounds__(256) void k_loop(
    u16* hb, float* cbuf,
    const u16* UwB, const float* U_b, const float* v_w,
    const u16* WsB, const u16* imgb,
    const u16* fWhT, const float* fb_b,
    float* ctx, float* pre1,
    const u16* Wc2, const float* cbias,
    u16* hAll, float* alphas) {
  cg::grid_group grid = cg::this_grid();
  __shared__ __align__(16) char smem[46080];
  int bid = blockIdx.x, tid = threadIdx.x;
  int lane = tid & 63, w = tid >> 6;

  for (int t = 0; t < 20; ++t) {
    // ---------------- phase 1 ----------------
    if (bid < 128) {
      int b = bid;
      float* h_s = (float*)smem;             // 512
      float* v_s = (float*)(smem + 2048);    // 512
      float* p4 = (float*)(smem + 4096);     // 4*512
      float* al_s = (float*)(smem + 12288);  // 256
      float* ctxp = (float*)(smem + 13312);  // 4*2048
      {
        u32 hv = *(const u32*)(hb + b * 512 + tid * 2);
        h_s[tid * 2] = bf2f((u16)(hv & 0xffff));
        h_s[tid * 2 + 1] = bf2f((u16)(hv >> 16));
        float2 vv = *(const float2*)(v_w + tid * 2);
        v_s[tid * 2] = vv.x;
        v_s[tid * 2 + 1] = vv.y;
      }
      __syncthreads();
      // hU: wave w covers k-slice; lane covers n = lane*8..+8
      {
        float acc[8] = {};
        const u16* up = UwB + (size_t)(w * 128) * 512 + lane * 8;
#pragma unroll 4
        for (int k = 0; k < 128; ++k) {
          float hk = h_s[w * 128 + k];
          uint4 uv = *(const uint4*)(up + (size_t)k * 512);
          const u16* uu = (const u16*)&uv;
#pragma unroll
          for (int j = 0; j < 8; ++j) acc[j] += hk * bf2f(uu[j]);
        }
        float* dst = p4 + w * 512 + lane * 8;
#pragma unroll
        for (int j = 0; j < 8; ++j) dst[j] = acc[j];
      }
      __syncthreads();
      {
        int n = tid * 2;
#pragma unroll
        for (int j = 0; j < 2; ++j) {
          p4[n + j] = U_b[n + j] + p4[n + j] + p4[512 + n + j] + p4[1024 + n + j] +
                      p4[1536 + n + j];
        }
      }
      __syncthreads();
      const float* hu_s = p4;
      // e[p] = sum_h tanh(Ws + hU) * v
      const u16* wsrow = WsB + (size_t)b * 196 * 512 + lane * 8;
      for (int p = w; p < 196; p += 4) {
        uint4 pk = *(const uint4*)(wsrow + (size_t)p * 512);
        const u16* uu = (const u16*)&pk;
        float e = 0.f;
#pragma unroll
        for (int j = 0; j < 8; ++j) {
          int hch = lane * 8 + j;
          e += tanh_f(bf2f(uu[j]) + hu_s[hch]) * v_s[hch];
        }
#pragma unroll
        for (int off = 32; off; off >>= 1) e += __shfl_xor(e, off);
        if (lane == 0) al_s[p] = e;  // v_b cancels in softmax
      }
      __syncthreads();
      if (w == 0) {
        float mx = -1e30f;
        for (int q = lane; q < 196; q += 64) mx = fmaxf(mx, al_s[q]);
#pragma unroll
        for (int off = 32; off; off >>= 1) mx = fmaxf(mx, __shfl_xor(mx, off));
        float ssum = 0.f;
        for (int q = lane; q < 196; q += 64) {
          float ex = __expf(al_s[q] - mx);
          al_s[q] = ex;
          ssum += ex;
        }
#pragma unroll
        for (int off = 32; off; off >>= 1) ssum += __shfl_xor(ssum, off);
        float inv = 1.f / ssum;
        for (int q = lane; q < 196; q += 64) al_s[q] *= inv;
      }
      __syncthreads();
      if (tid < 196) alphas[(size_t)b * 3920 + (size_t)t * 196 + tid] = al_s[tid];
      // ctx: wave w covers p-slice; lane covers 32 channels
      {
        float a32[32] = {};
        const u16* ib = imgb + (size_t)b * 196 * 2048 + lane * 32;
        for (int p = w; p < 196; p += 4) {
          float ap = al_s[p];
          const uint4* rp = (const uint4*)(ib + (size_t)p * 2048);
#pragma unroll
          for (int q = 0; q < 4; ++q) {
            uint4 v = rp[q];
            const u16* uu = (const u16*)&v;
#pragma unroll
            for (int j = 0; j < 8; ++j) a32[q * 8 + j] += ap * bf2f(uu[j]);
          }
        }
        float* dst = ctxp + w * 2048 + lane * 32;
#pragma unroll
        for (int j = 0; j < 32; ++j) dst[j] = a32[j];
      }
      __syncthreads();
      {
        int c0 = tid * 8;
#pragma unroll
        for (int j = 0; j < 8; ++j) {
          int c = c0 + j;
          ctx[(size_t)b * 2048 + c] =
              ctxp[c] + ctxp[2048 + c] + ctxp[4096 + c] + ctxp[6144 + c];
        }
      }
    } else {
      // gemm1: pre1[128,4096] = h @ [fbT|WhhT]^T (+fb_b on left half)
      u16* Asm = (u16*)smem;           // 64*72
      u16* Bsm = (u16*)(smem + 9216);  // 64*72
      int g = bid - 128;
      int mt = g >> 6, nt = g & 63;
      long m0 = (long)mt * 64, n0 = (long)nt * 64;
      int srow = tid >> 3, schk = tid & 7;
      f32x4 acc[4] = {};
      const u16* Ap0 = hb + (m0 + srow) * 512 + schk * 8;
      const u16* Ap1 = hb + (m0 + srow + 32) * 512 + schk * 8;
      const u16* Bp0 = fWhT + (n0 + srow) * 512 + schk * 8;
      const u16* Bp1 = fWhT + (n0 + srow + 32) * 512 + schk * 8;
      u16* Aw0 = Asm + srow * 72 + schk * 8;
      u16* Aw1 = Asm + (srow + 32) * 72 + schk * 8;
      u16* Bw0 = Bsm + srow * 72 + schk * 8;
      u16* Bw1 = Bsm + (srow + 32) * 72 + schk * 8;
      const u16* Ar = Asm + (w * 16 + (lane & 15)) * 72 + (lane >> 4) * 8;
      const u16* Br = Bsm + (lane & 15) * 72 + (lane >> 4) * 8;
#pragma unroll 1
      for (int k0 = 0; k0 < 512; k0 += 64) {
        uint4 a0 = *(const uint4*)(Ap0 + k0);
        uint4 a1 = *(const uint4*)(Ap1 + k0);
        uint4 b0 = *(const uint4*)(Bp0 + k0);
        uint4 b1 = *(const uint4*)(Bp1 + k0);
        __syncthreads();
        *(uint4*)Aw0 = a0;
        *(uint4*)Aw1 = a1;
        *(uint4*)Bw0 = b0;
        *(uint4*)Bw1 = b1;
        __syncthreads();
#pragma unroll
        for (int kk = 0; kk < 2; ++kk) {
          bf16x8 af = *(const bf16x8*)(Ar + kk * 32);
#pragma unroll
          for (int sn = 0; sn < 4; ++sn) {
            bf16x8 bfr = *(const bf16x8*)(Br + sn * 16 * 72 + kk * 32);
            acc[sn] = __builtin_amdgcn_mfma_f32_16x16x32_bf16(af, bfr, acc[sn], 0, 0, 0);
          }
        }
      }
      int cb = lane & 15, rb = (lane >> 4) * 4;
#pragma unroll
      for (int sn = 0; sn < 4; ++sn) {
#pragma unroll
        for (int r = 0; r < 4; ++r) {
          long m = m0 + w * 16 + rb + r;
          long n = n0 + sn * 16 + cb;
          float v = acc[sn][r];
          if (n < 2048) v += fb_b[n];
          pre1[m * 4096 + n] = v;
        }
      }
    }
    grid.sync();
    // ---------------- phase 2: 256 x 32x32 gate tiles ----------------
    {
      int mt = bid >> 6, nt = bid & 63;
      int m0 = mt * 32, n0 = nt * 32;
      u16* Asm2 = (u16*)smem;            // 32*72
      u16* Bsm2 = (u16*)(smem + 4608);   // 32*72
      float* gtile = (float*)(smem + 9216);  // [32][36]
      int arow = tid >> 3, achk = tid & 7;
      int sm = w >> 1, sn = w & 1;
      f32x4 acc = {};
      const float* pA = pre1 + (size_t)(m0 + arow) * 4096 + achk * 8;
      const float* pC = ctx + (size_t)(m0 + arow) * 2048 + achk * 8;
      const u16* pB = Wc2 + (size_t)(n0 + arow) * 2048 + achk * 8;
      u16* Aw = Asm2 + arow * 72 + achk * 8;
      u16* Bw = Bsm2 + arow * 72 + achk * 8;
      const u16* Ar = Asm2 + (sm * 16 + (lane & 15)) * 72 + (lane >> 4) * 8;
      const u16* Br = Bsm2 + (sn * 16 + (lane & 15)) * 72 + (lane >> 4) * 8;
#pragma unroll 1
      for (int k0 = 0; k0 < 2048; k0 += 64) {
        float4 g0 = *(const float4*)(pA + k0);
        float4 g1 = *(const float4*)(pA + k0 + 4);
        float4 c0v = *(const float4*)(pC + k0);
        float4 c1v = *(const float4*)(pC + k0 + 4);
        uint4 bv = *(const uint4*)(pB + k0);
        union { u16 u[8]; uint4 v; } av;
        av.u[0] = f2bf(sigm_f(g0.x) * c0v.x);
        av.u[1] = f2bf(sigm_f(g0.y) * c0v.y);
        av.u[2] = f2bf(sigm_f(g0.z) * c0v.z);
        av.u[3] = f2bf(sigm_f(g0.w) * c0v.w);
        av.u[4] = f2bf(sigm_f(g1.x) * c1v.x);
        av.u[5] = f2bf(sigm_f(g1.y) * c1v.y);
        av.u[6] = f2bf(sigm_f(g1.z) * c1v.z);
        av.u[7] = f2bf(sigm_f(g1.w) * c1v.w);
        __syncthreads();
        *(uint4*)Aw = av.v;
        *(uint4*)Bw = bv;
        __syncthreads();
#pragma unroll
        for (int kk = 0; kk < 2; ++kk) {
          bf16x8 a = *(const bf16x8*)(Ar + kk * 32);
          bf16x8 b = *(const bf16x8*)(Br + kk * 32);
          acc = __builtin_amdgcn_mfma_f32_16x16x32_bf16(a, b, acc, 0, 0, 0);
        }
      }
      int cb2 = lane & 15, rb2 = (lane >> 4) * 4;
#pragma unroll
      for (int r = 0; r < 4; ++r) {
        int mrow = sm * 16 + rb2 + r;
        int ncol = sn * 16 + cb2;
        gtile[mrow * 36 + ncol] =
            acc[r] + pre1[(size_t)(m0 + mrow) * 4096 + 2048 + n0 + ncol] +
            cbias[n0 + ncol];
      }
      __syncthreads();
      {
        int m = tid >> 3, chl = tid & 7;
        float iv = gtile[m * 36 + chl * 4 + 0];
        float fv = gtile[m * 36 + chl * 4 + 1];
        float gv = gtile[m * 36 + chl * 4 + 2];
        float ov = gtile[m * 36 + chl * 4 + 3];
        int bg = m0 + m;
        int ch = (n0 >> 2) + chl;
        size_t ci = (size_t)bg * 512 + ch;
        float cn = sigm_f(fv) * cbuf[ci] + sigm_f(iv) * tanh_f(gv);
        float hh = sigm_f(ov) * tanh_f(cn);
        cbuf[ci] = cn;
        u16 hv = f2bf(hh);
        hb[ci] = hv;
        hAll[((size_t)t * 128 + bg) * 512 + ch] = hv;
      }
    }
    grid.sync();
  }
}

extern "C" void kernel_launch(void* const* d_in, const int* in_sizes, int n_in,
                              void* d_out, int out_size, void* d_ws, size_t ws_size,
                              hipStream_t stream) {
  const float* img = (const float*)d_in[0];
  // d_in[1] captions: static T=20; d_in[7] v_b: cancels in softmax
  const float* U_w = (const float*)d_in[2];
  const float* U_b = (const float*)d_in[3];
  const float* W_w = (const float*)d_in[4];
  const float* W_b = (const float*)d_in[5];
  const float* v_w = (const float*)d_in[6];
  const float* ih_w = (const float*)d_in[8];
  const float* ih_b = (const float*)d_in[9];
  const float* ic_w = (const float*)d_in[10];
  const float* ic_b = (const float*)d_in[11];
  const float* fb_w = (const float*)d_in[12];
  const float* fb_b = (const float*)d_in[13];
  const float* out_w = (const float*)d_in[14];
  const float* out_b = (const float*)d_in[15];
  const float* emb = (const float*)d_in[16];
  const float* Wih = (const float*)d_in[17];
  const float* Whh = (const float*)d_in[18];
  const float* bih = (const float*)d_in[19];
  const float* bhh = (const float*)d_in[20];
  float* preds = (float*)d_out;              // [128,20,10000]
  float* alphas = (float*)d_out + 25600000;  // [128,20,196]

  char* ws = (char*)d_ws;
  size_t off = 0;
  auto alloc = [&](size_t bytes) {
    void* p = ws + off;
    off = (off + bytes + 255) & ~(size_t)255;
    return p;
  };
  u16* imgb = (u16*)alloc((size_t)128 * 196 * 2048 * 2);
  u16* avgb = (u16*)alloc((size_t)128 * 2048 * 2);
  u16* WsB = (u16*)alloc((size_t)128 * 196 * 512 * 2);
  u16* WwT = (u16*)alloc((size_t)512 * 2048 * 2);
  u16* UwB = (u16*)alloc((size_t)512 * 512 * 2);
  u16* ihT = (u16*)alloc((size_t)512 * 2048 * 2);
  u16* icT = (u16*)alloc((size_t)512 * 2048 * 2);
  u16* fWhT = (u16*)alloc((size_t)4096 * 512 * 2);  // [fbT | permuted WhhT]
  u16* Wc2 = (u16*)alloc((size_t)2048 * 2048 * 2);  // permuted Wih_ctx^T
  u16* owT = (u16*)alloc((size_t)10112 * 512 * 2);
  float* cbias = (float*)alloc(2048 * 4);
  u16* hb = (u16*)alloc((size_t)128 * 512 * 2);
  float* cbuf = (float*)alloc((size_t)128 * 512 * 4);
  float* ctx = (float*)alloc((size_t)128 * 2048 * 4);
  float* pre1 = (float*)alloc((size_t)128 * 4096 * 4);
  u16* hAll = (u16*)alloc((size_t)2560 * 512 * 2);
  if (off > ws_size) return;
  (void)in_sizes; (void)n_in; (void)out_size;

  dim3 tb(32, 8);
  // --- one-time precompute ---
  k_f32_to_bf16<<<25088, 256, 0, stream>>>(img, imgb);
  k_f32_to_bf16<<<128, 256, 0, stream>>>(U_w, UwB);
  k_avg<<<dim3(4, 128), 256, 0, stream>>>(imgb, avgb);
  k_transpose_bf16<false><<<dim3(16, 64), tb, 0, stream>>>(W_w, 2048, 512, 512, WwT, 2048);
  k_transpose_bf16<false><<<dim3(16, 64), tb, 0, stream>>>(ih_w, 2048, 512, 512, ihT, 2048);
  k_transpose_bf16<false><<<dim3(16, 64), tb, 0, stream>>>(ic_w, 2048, 512, 512, icT, 2048);
  k_transpose_bf16<false><<<dim3(64, 16), tb, 0, stream>>>(fb_w, 512, 2048, 2048, fWhT, 512);
  k_transpose_bf16<true><<<dim3(64, 16), tb, 0, stream>>>(Whh, 512, 2048, 2048,
                                                          fWhT + (size_t)2048 * 512, 512);
  k_transpose_bf16<true><<<dim3(64, 64), tb, 0, stream>>>(Wih + 512 * 2048, 2048, 2048,
                                                          2048, Wc2, 2048);
  k_transpose_bf16<false><<<dim3(316, 16), tb, 0, stream>>>(out_w, 512, 10000, 10112, owT, 512);
  k_cbias<<<8, 256, 0, stream>>>(emb, Wih, bih, bhh, cbias);
  // W_s = img @ W_w + W_b
  k_gemm128<EPI128_WS><<<784, 256, 0, stream>>>(imgb, WwT, 2048, 4, W_b, nullptr, WsB, 0);
  // h0 / c0
  k_gemm64<EPI_TANH_H><<<16, 256, 0, stream>>>(avgb, ihT, 2048, 8, ih_b, nullptr, hb);
  k_gemm64<EPI_TANH_C><<<16, 256, 0, stream>>>(avgb, icT, 2048, 8, ic_b, cbuf, nullptr);

  // --- persistent cooperative loop (20 steps, 2 grid syncs/step) ---
  {
    void* args[] = {&hb, &cbuf, &UwB, &U_b, &v_w, &WsB, &imgb, &fWhT, &fb_b,
                    &ctx, &pre1, &Wc2, &cbias, &hAll, &alphas};
    hipLaunchCooperativeKernel((const void*)k_loop, dim3(256), dim3(256), args, 0, stream);
  }

  // preds = hAll @ out_w + out_b
  k_gemm128<EPI128_OUT><<<20 * 79, 256, 0, stream>>>(hAll, owT, 512, 79, out_b,
                                                     preds, nullptr, 10000);
}